// Round 2
// baseline (1042.755 us; speedup 1.0000x reference)
//
#include <hip/hip_runtime.h>
#include <cstdint>

typedef __attribute__((ext_vector_type(4))) float f32x4;
typedef __attribute__((ext_vector_type(8))) short bf16x8;
typedef __attribute__((ext_vector_type(4))) short bf16x4;

#define DEV static __device__ __forceinline__

// round-to-nearest-even f32 -> bf16 (bit pattern)
DEV unsigned short f2bf(float f) {
    union { float f; unsigned int u; } v; v.f = f;
    unsigned int u = v.u;
    return (unsigned short)((u + 0x7FFFu + ((u >> 16) & 1u)) >> 16);
}

// async global->LDS 16B per lane; LDS dest = wave-uniform base + lane*16
DEV void async_cp16(const void* g, void* l) {
    __builtin_amdgcn_global_load_lds(
        (const __attribute__((address_space(1))) unsigned int*)g,
        (__attribute__((address_space(3))) unsigned int*)l,
        16, 0, 0);
}

// ---------------------------------------------------------------------------
// Kernel 0: weight prep.
//  w1t[n][k] = bf16(w0[k]*w1[k][n])   (512 x 1024, k contiguous)
//  w2t[n][k] = bf16(w0[k]*w2[k][n])
//  w3t[j][n] = bf16(w3[n][j])         (1024 x 512, n contiguous)
// ---------------------------------------------------------------------------
__global__ void prep_w(const float* __restrict__ w0, const float* __restrict__ w1,
                       const float* __restrict__ w2, const float* __restrict__ w3,
                       unsigned short* __restrict__ w1t, unsigned short* __restrict__ w2t,
                       unsigned short* __restrict__ w3t) {
    int t = blockIdx.x * 256 + threadIdx.x;   // 0 .. 3*524288-1
    int sec = t >> 19;
    int idx = t & 524287;
    if (sec == 0) {
        int n = idx >> 10, k = idx & 1023;
        w1t[idx] = f2bf(w0[k] * w1[k * 512 + n]);
    } else if (sec == 1) {
        int n = idx >> 10, k = idx & 1023;
        w2t[idx] = f2bf(w0[k] * w2[k * 512 + n]);
    } else {
        int j = idx >> 9, n = idx & 511;
        w3t[idx] = f2bf(w3[n * 1024 + j]);
    }
}

// ---------------------------------------------------------------------------
// Kernel 0b: RMSNorm fold. xb[row][k] = bf16(x[row][k] * rsqrt(mean(x^2)))
// One wave per row; 16 f32/lane; shuffle-reduce sumsq.
// ---------------------------------------------------------------------------
__global__ __launch_bounds__(256)
void prep_x(const float* __restrict__ x, unsigned short* __restrict__ xb) {
    const int wv = threadIdx.x >> 6, lane = threadIdx.x & 63;
    const int stride = gridDim.x * 4;
    for (int row = blockIdx.x * 4 + wv; row < 131072; row += stride) {
        const float* xr = x + (long)row * 1024;
        f32x4 v[4];
        float s = 0.f;
#pragma unroll
        for (int c = 0; c < 4; ++c) {
            v[c] = *(const f32x4*)(xr + c * 256 + lane * 4);
            s += v[c].x * v[c].x + v[c].y * v[c].y + v[c].z * v[c].z + v[c].w * v[c].w;
        }
#pragma unroll
        for (int off = 32; off > 0; off >>= 1) s += __shfl_xor(s, off, 64);
        float l = rsqrtf(s * (1.0f / 1024.0f));
        unsigned short* xo = xb + (long)row * 1024;
#pragma unroll
        for (int c = 0; c < 4; ++c) {
            bf16x4 b;
            b.x = (short)f2bf(v[c].x * l);
            b.y = (short)f2bf(v[c].y * l);
            b.z = (short)f2bf(v[c].z * l);
            b.w = (short)f2bf(v[c].w * l);
            *(bf16x4*)(xo + c * 256 + lane * 4) = b;
        }
    }
}

// ---------------------------------------------------------------------------
// Kernel 1: dual GEMM (gate/up) + SiLU-gate -> x3 (bf16, M x 512)
// Pure bf16 GEMM on pre-normalized xb. 128x128 tiles, BK=64, 256 threads.
// All tiles staged via global_load_lds (width 16), source-swizzled.
// ---------------------------------------------------------------------------
__global__ __launch_bounds__(256, 3)
void gate_gemm(const unsigned short* __restrict__ xb,
               const unsigned short* __restrict__ w1t,
               const unsigned short* __restrict__ w2t,
               unsigned short* __restrict__ x3) {
    __shared__ unsigned short aLds[128 * 64];
    __shared__ unsigned short b1Lds[128 * 64];
    __shared__ unsigned short b2Lds[128 * 64];

    const int tid = threadIdx.x;
    const int lane = tid & 63;
    const int wv = tid >> 6;
    const int wr = wv >> 1, wc = wv & 1;
    const int lhi = lane >> 4, llo = lane & 15;

    int bid = blockIdx.x;
    int wgid = (bid & 7) * 512 + (bid >> 3);     // 4096 % 8 == 0, bijective
    const int mt = wgid >> 2, nt = wgid & 3;
    const unsigned short* xa = xb + (long)mt * 128 * 1024;
    const int n0 = nt * 128;

    f32x4 accg[4][4], accu[4][4];
#pragma unroll
    for (int i = 0; i < 4; ++i)
#pragma unroll
        for (int j = 0; j < 4; ++j) {
            accg[i][j] = (f32x4){0.f, 0.f, 0.f, 0.f};
            accu[i][j] = (f32x4){0.f, 0.f, 0.f, 0.f};
        }

    for (int kt = 0; kt < 16; ++kt) {
        __syncthreads();
#pragma unroll
        for (int i = 0; i < 4; ++i) {
            int c = i * 256 + wv * 64 + lane;    // 16B chunks, 1024 per tile
            int row = c >> 3;
            int sslot = (c & 7) ^ (row & 7);     // inverse-swizzled source
            int lbase = (i * 256 + wv * 64) * 8; // wave-uniform, ushort units
            async_cp16(xa + (long)row * 1024 + kt * 64 + sslot * 8, aLds + lbase);
            long goff = (long)(n0 + row) * 1024 + kt * 64 + sslot * 8;
            async_cp16(w1t + goff, b1Lds + lbase);
            async_cp16(w2t + goff, b2Lds + lbase);
        }
        __syncthreads();
#pragma unroll
        for (int kq = 0; kq < 2; ++kq) {
            const int q = kq * 4 + lhi;          // 16B slot index within row
            bf16x8 af[4], b1f[4], b2f[4];
#pragma unroll
            for (int i = 0; i < 4; ++i) {
                int r = wr * 64 + i * 16 + llo;
                af[i] = *(const bf16x8*)(aLds + r * 64 + ((q ^ (r & 7)) << 3));
            }
#pragma unroll
            for (int j = 0; j < 4; ++j) {
                int r = wc * 64 + j * 16 + llo;
                int off = r * 64 + ((q ^ (r & 7)) << 3);
                b1f[j] = *(const bf16x8*)(b1Lds + off);
                b2f[j] = *(const bf16x8*)(b2Lds + off);
            }
#pragma unroll
            for (int i = 0; i < 4; ++i)
#pragma unroll
                for (int j = 0; j < 4; ++j) {
                    accg[i][j] = __builtin_amdgcn_mfma_f32_16x16x32_bf16(af[i], b1f[j], accg[i][j], 0, 0, 0);
                    accu[i][j] = __builtin_amdgcn_mfma_f32_16x16x32_bf16(af[i], b2f[j], accu[i][j], 0, 0, 0);
                }
        }
    }
    // ---- epilogue: SiLU-gate, store bf16 ----------------------------------
    unsigned short* x3p = x3 + (long)mt * 128 * 512 + n0;
#pragma unroll
    for (int i = 0; i < 4; ++i) {
#pragma unroll
        for (int r = 0; r < 4; ++r) {
            int rloc = wr * 64 + i * 16 + (lhi << 2) + r;   // C/D: row=(lane>>4)*4+reg
#pragma unroll
            for (int j = 0; j < 4; ++j) {
                float g = accg[i][j][r];
                float u = accu[i][j][r];
                float s = (g / (1.0f + __expf(-g))) * u;
                x3p[(long)rloc * 512 + wc * 64 + j * 16 + llo] = f2bf(s);  // col=lane&15
            }
        }
    }
}

// ---------------------------------------------------------------------------
// Kernel 1-fallback (round-1 fused version, used only if ws too small)
// ---------------------------------------------------------------------------
__global__ __launch_bounds__(256, 2)
void ffn_gate_fused(const float* __restrict__ x,
                    const unsigned short* __restrict__ w1t,
                    const unsigned short* __restrict__ w2t,
                    unsigned short* __restrict__ x3) {
    __shared__ unsigned short aLds[128][72];
    __shared__ unsigned short b1Lds[128 * 64];
    __shared__ unsigned short b2Lds[128 * 64];
    __shared__ float part[128][16];
    __shared__ float lrow[128];

    const int tid = threadIdx.x;
    const int lane = tid & 63;
    const int wv = tid >> 6;
    const int wr = wv >> 1, wc = wv & 1;
    const int lhi = lane >> 4, llo = lane & 15;

    int bid = blockIdx.x;
    int wgid = (bid & 7) * 512 + (bid >> 3);
    const int mt = wgid >> 2, nt = wgid & 3;
    const float* xA = x + (long)mt * 128 * 1024;
    const int n0 = nt * 128;

    for (int i = tid; i < 128 * 16; i += 256) (&part[0][0])[i] = 0.0f;

    f32x4 accg[4][4], accu[4][4];
#pragma unroll
    for (int i = 0; i < 4; ++i)
#pragma unroll
        for (int j = 0; j < 4; ++j) {
            accg[i][j] = (f32x4){0.f, 0.f, 0.f, 0.f};
            accu[i][j] = (f32x4){0.f, 0.f, 0.f, 0.f};
        }

    const int prow = tid >> 4;
    const int pcol = tid & 15;

    for (int kt = 0; kt < 16; ++kt) {
        __syncthreads();
        {
            const float* xs = xA + kt * 64;
#pragma unroll
            for (int i = 0; i < 8; ++i) {
                int chunk = i * 256 + tid;
                int row = chunk >> 4;
                int c4 = (chunk & 15) << 2;
                f32x4 v = *(const f32x4*)(xs + row * 1024 + c4);
                part[i * 16 + prow][pcol] += v.x * v.x + v.y * v.y + v.z * v.z + v.w * v.w;
                bf16x4 b;
                b.x = (short)f2bf(v.x); b.y = (short)f2bf(v.y);
                b.z = (short)f2bf(v.z); b.w = (short)f2bf(v.w);
                *(bf16x4*)&aLds[row][c4] = b;
            }
        }
#pragma unroll
        for (int i = 0; i < 4; ++i) {
            int c = i * 256 + wv * 64 + lane;
            int row = c >> 3;
            int sslot = (c & 7) ^ (row & 7);
            long goff = (long)(n0 + row) * 1024 + kt * 64 + sslot * 8;
            int lbase = (i * 256 + wv * 64) * 8;
            async_cp16(w1t + goff, b1Lds + lbase);
            async_cp16(w2t + goff, b2Lds + lbase);
        }
        __syncthreads();
#pragma unroll
        for (int kq = 0; kq < 2; ++kq) {
            const int koff = kq * 32 + lhi * 8;
            const int q = kq * 4 + lhi;
            bf16x8 af[4], b1f[4], b2f[4];
#pragma unroll
            for (int i = 0; i < 4; ++i) {
                int r = wr * 64 + i * 16 + llo;
                af[i] = *(const bf16x8*)&aLds[r][koff];
            }
#pragma unroll
            for (int j = 0; j < 4; ++j) {
                int r = wc * 64 + j * 16 + llo;
                int off = r * 64 + ((q ^ (r & 7)) << 3);
                b1f[j] = *(const bf16x8*)(b1Lds + off);
                b2f[j] = *(const bf16x8*)(b2Lds + off);
            }
#pragma unroll
            for (int i = 0; i < 4; ++i)
#pragma unroll
                for (int j = 0; j < 4; ++j) {
                    accg[i][j] = __builtin_amdgcn_mfma_f32_16x16x32_bf16(af[i], b1f[j], accg[i][j], 0, 0, 0);
                    accu[i][j] = __builtin_amdgcn_mfma_f32_16x16x32_bf16(af[i], b2f[j], accu[i][j], 0, 0, 0);
                }
        }
    }
    __syncthreads();
    if (tid < 128) {
        float s = 0.f;
#pragma unroll
        for (int c = 0; c < 16; ++c) s += part[tid][c];
        lrow[tid] = 1.0f / sqrtf(s * (1.0f / 1024.0f));
    }
    __syncthreads();
    unsigned short* x3p = x3 + (long)mt * 128 * 512 + n0;
#pragma unroll
    for (int i = 0; i < 4; ++i) {
#pragma unroll
        for (int r = 0; r < 4; ++r) {
            int rloc = wr * 64 + i * 16 + (lhi << 2) + r;
            float l = lrow[rloc];
#pragma unroll
            for (int j = 0; j < 4; ++j) {
                float g = accg[i][j][r] * l;
                float u = accu[i][j][r] * l;
                float s = (g / (1.0f + __expf(-g))) * u;
                x3p[(long)rloc * 512 + wc * 64 + j * 16 + llo] = f2bf(s);
            }
        }
    }
}

// ---------------------------------------------------------------------------
// Kernel 2: out = x3 @ w3t  (M x 1024 fp32). 128x128 tiles, K=512, BK=64.
// ---------------------------------------------------------------------------
__global__ __launch_bounds__(256, 3)
void down_gemm(const unsigned short* __restrict__ x3,
               const unsigned short* __restrict__ w3t,
               float* __restrict__ out) {
    __shared__ unsigned short aLds[128 * 64];
    __shared__ unsigned short bLds[128 * 64];

    const int tid = threadIdx.x;
    const int lane = tid & 63;
    const int wv = tid >> 6;
    const int wr = wv >> 1, wc = wv & 1;
    const int lhi = lane >> 4, llo = lane & 15;

    int bid = blockIdx.x;
    int wgid = (bid & 7) * 1024 + (bid >> 3);    // 8192 % 8 == 0, bijective
    const int mt = wgid >> 3, nt = wgid & 7;
    const unsigned short* xa = x3 + (long)mt * 128 * 512;
    const int n0 = nt * 128;

    f32x4 acc[4][4];
#pragma unroll
    for (int i = 0; i < 4; ++i)
#pragma unroll
        for (int j = 0; j < 4; ++j) acc[i][j] = (f32x4){0.f, 0.f, 0.f, 0.f};

    for (int kt = 0; kt < 8; ++kt) {
        __syncthreads();
#pragma unroll
        for (int i = 0; i < 4; ++i) {
            int c = i * 256 + wv * 64 + lane;
            int row = c >> 3;
            int sslot = (c & 7) ^ (row & 7);
            int lbase = (i * 256 + wv * 64) * 8;
            async_cp16(xa + (long)row * 512 + kt * 64 + sslot * 8, aLds + lbase);
            async_cp16(w3t + (long)(n0 + row) * 512 + kt * 64 + sslot * 8, bLds + lbase);
        }
        __syncthreads();
#pragma unroll
        for (int kq = 0; kq < 2; ++kq) {
            const int q = kq * 4 + lhi;
            bf16x8 af[4], bf[4];
#pragma unroll
            for (int i = 0; i < 4; ++i) {
                int r = wr * 64 + i * 16 + llo;
                af[i] = *(const bf16x8*)(aLds + r * 64 + ((q ^ (r & 7)) << 3));
            }
#pragma unroll
            for (int j = 0; j < 4; ++j) {
                int r = wc * 64 + j * 16 + llo;
                bf[j] = *(const bf16x8*)(bLds + r * 64 + ((q ^ (r & 7)) << 3));
            }
#pragma unroll
            for (int i = 0; i < 4; ++i)
#pragma unroll
                for (int j = 0; j < 4; ++j)
                    acc[i][j] = __builtin_amdgcn_mfma_f32_16x16x32_bf16(af[i], bf[j], acc[i][j], 0, 0, 0);
        }
    }
    float* op = out + (long)mt * 128 * 1024 + n0;
#pragma unroll
    for (int i = 0; i < 4; ++i) {
#pragma unroll
        for (int r = 0; r < 4; ++r) {
            int rloc = wr * 64 + i * 16 + (lhi << 2) + r;
#pragma unroll
            for (int j = 0; j < 4; ++j)
                op[(long)rloc * 1024 + wc * 64 + j * 16 + llo] = acc[i][j][r];
        }
    }
}

// ---------------------------------------------------------------------------
extern "C" void kernel_launch(void* const* d_in, const int* in_sizes, int n_in,
                              void* d_out, int out_size, void* d_ws, size_t ws_size,
                              hipStream_t stream) {
    const float* x  = (const float*)d_in[0];
    const float* w0 = (const float*)d_in[1];
    const float* w1 = (const float*)d_in[2];
    const float* w2 = (const float*)d_in[3];
    const float* w3 = (const float*)d_in[4];
    float* out = (float*)d_out;

    unsigned short* w1t = (unsigned short*)d_ws;            // 1MB
    unsigned short* w2t = w1t + 512 * 1024;                 // 1MB
    unsigned short* w3t = w2t + 512 * 1024;                 // 1MB
    unsigned short* x3  = w3t + 1024 * 512;                 // 128MB
    unsigned short* xb  = x3 + (size_t)131072 * 512;        // 256MB

    const size_t need_full = 3u * 1048576u + 134217728u + 268435456u;

    prep_w<<<dim3(6144), dim3(256), 0, stream>>>(w0, w1, w2, w3, w1t, w2t, w3t);
    if (ws_size >= need_full) {
        prep_x<<<dim3(2048), dim3(256), 0, stream>>>(x, xb);
        gate_gemm<<<dim3(4096), dim3(256), 0, stream>>>(xb, w1t, w2t, x3);
    } else {
        ffn_gate_fused<<<dim3(4096), dim3(256), 0, stream>>>(x, w1t, w2t, x3);
    }
    down_gemm<<<dim3(8192), dim3(256), 0, stream>>>(x3, w3t, out);
}

// Round 3
// 917.588 us; speedup vs baseline: 1.1364x; 1.1364x over previous
//
#include <hip/hip_runtime.h>
#include <cstdint>

typedef __attribute__((ext_vector_type(4))) float f32x4;
typedef __attribute__((ext_vector_type(8))) short bf16x8;
typedef __attribute__((ext_vector_type(4))) short bf16x4;

#define DEV static __device__ __forceinline__

// round-to-nearest-even f32 -> bf16 (bit pattern)
DEV unsigned short f2bf(float f) {
    union { float f; unsigned int u; } v; v.f = f;
    unsigned int u = v.u;
    return (unsigned short)((u + 0x7FFFu + ((u >> 16) & 1u)) >> 16);
}

// async global->LDS 16B per lane; LDS dest = wave-uniform base + lane*16
DEV void async_cp16(const void* g, void* l) {
    __builtin_amdgcn_global_load_lds(
        (const __attribute__((address_space(1))) unsigned int*)g,
        (__attribute__((address_space(3))) unsigned int*)l,
        16, 0, 0);
}

// stage one pair of 128x64 bf16 tiles (A,B) into LDS, source-swizzled so a
// swizzled ds_read_b128 is bank-conflict-free. ga/gb pre-offset to tile+kt.
DEV void stage2(const unsigned short* __restrict__ ga,
                const unsigned short* __restrict__ gb,
                unsigned short* la, unsigned short* lb,
                int tid, int gpitch) {
#pragma unroll
    for (int i = 0; i < 4; ++i) {
        int c = i * 256 + tid;                // 1024 chunks of 16B
        int row = c >> 3;
        int ss = (c & 7) ^ (row & 7);         // inverse-swizzled source slot
        long go = (long)row * gpitch + ss * 8;
        int lo = (i * 256 + (tid & 192)) * 8; // wave-uniform LDS base (ushorts)
        async_cp16(ga + go, la + lo);
        async_cp16(gb + go, lb + lo);
    }
}

// ---------------------------------------------------------------------------
// Kernel 0: weight prep.
//  w12t[n][k]: n even -> bf16(w0[k]*w1[k][n/2]), n odd -> bf16(w0[k]*w2[k][n/2])
//              (1024 x 1024, k contiguous; gate/up column-interleaved)
//  w3t[j][n] = bf16(w3[n][j])   (1024 x 512, n contiguous)
// ---------------------------------------------------------------------------
__global__ void prep_w(const float* __restrict__ w0, const float* __restrict__ w1,
                       const float* __restrict__ w2, const float* __restrict__ w3,
                       unsigned short* __restrict__ w12t, unsigned short* __restrict__ w3t) {
    int t = blockIdx.x * 256 + threadIdx.x;   // 0 .. 1572863
    if (t < 1048576) {
        int n = t >> 10, k = t & 1023;
        const float* src = (n & 1) ? w2 : w1;
        w12t[t] = f2bf(w0[k] * src[k * 512 + (n >> 1)]);
    } else {
        int idx = t - 1048576;
        int j = idx >> 9, n = idx & 511;
        w3t[idx] = f2bf(w3[n * 1024 + j]);
    }
}

// ---------------------------------------------------------------------------
// Kernel 0b: RMSNorm fold. xb[row][k] = bf16(x[row][k] * rsqrt(mean(x^2)))
// ---------------------------------------------------------------------------
__global__ __launch_bounds__(256)
void prep_x(const float* __restrict__ x, unsigned short* __restrict__ xb) {
    const int wv = threadIdx.x >> 6, lane = threadIdx.x & 63;
    const int stride = gridDim.x * 4;
    for (int row = blockIdx.x * 4 + wv; row < 131072; row += stride) {
        const float* xr = x + (long)row * 1024;
        f32x4 v[4];
        float s = 0.f;
#pragma unroll
        for (int c = 0; c < 4; ++c) {
            v[c] = *(const f32x4*)(xr + c * 256 + lane * 4);
            s += v[c].x * v[c].x + v[c].y * v[c].y + v[c].z * v[c].z + v[c].w * v[c].w;
        }
#pragma unroll
        for (int off = 32; off > 0; off >>= 1) s += __shfl_xor(s, off, 64);
        float l = rsqrtf(s * (1.0f / 1024.0f));
        unsigned short* xo = xb + (long)row * 1024;
#pragma unroll
        for (int c = 0; c < 4; ++c) {
            bf16x4 b;
            b.x = (short)f2bf(v[c].x * l);
            b.y = (short)f2bf(v[c].y * l);
            b.z = (short)f2bf(v[c].z * l);
            b.w = (short)f2bf(v[c].w * l);
            *(bf16x4*)(xo + c * 256 + lane * 4) = b;
        }
    }
}

// ---------------------------------------------------------------------------
// Kernel 1: x3 = silu_gate(xb @ w12t^T). Interleaved-B single GEMM.
// BM=128, BN=128 (=64 out cols), BK=64, 256 thr, double-buffered LDS (64KB),
// counted prefetch: STAGE(next) issued before COMPUTE(cur), one barrier/step.
// ---------------------------------------------------------------------------
__global__ __launch_bounds__(256, 2)
void gate_gemm(const unsigned short* __restrict__ xb,
               const unsigned short* __restrict__ w12t,
               unsigned short* __restrict__ x3) {
    __shared__ unsigned short aL[2][8192];    // 128x64 bf16 per buffer
    __shared__ unsigned short bL[2][8192];

    const int tid = threadIdx.x;
    const int lane = tid & 63;
    const int wv = tid >> 6;
    const int wr = wv >> 1, wc = wv & 1;
    const int lhi = lane >> 4, llo = lane & 15;

    int bid = blockIdx.x;                      // 8192 blocks
    int wgid = (bid & 7) * 1024 + (bid >> 3);  // bijective, 8 XCD chunks
    const int mt = wgid >> 3, nt = wgid & 7;
    const unsigned short* xa = xb + (long)mt * 128 * 1024;
    const unsigned short* ba = w12t + (long)nt * 128 * 1024;

    f32x4 acc[4][4];
#pragma unroll
    for (int i = 0; i < 4; ++i)
#pragma unroll
        for (int j = 0; j < 4; ++j) acc[i][j] = (f32x4){0.f, 0.f, 0.f, 0.f};

#define GG_COMPUTE(BUF)                                                        \
    {                                                                          \
        _Pragma("unroll")                                                      \
        for (int kq = 0; kq < 2; ++kq) {                                       \
            const int q = kq * 4 + lhi;                                        \
            bf16x8 af[4], bf[4];                                               \
            _Pragma("unroll")                                                  \
            for (int i = 0; i < 4; ++i) {                                      \
                int r = wr * 64 + i * 16 + llo;                                \
                af[i] = *(const bf16x8*)&aL[BUF][r * 64 + ((q ^ (r & 7)) << 3)];\
            }                                                                  \
            _Pragma("unroll")                                                  \
            for (int j = 0; j < 4; ++j) {                                      \
                int r = wc * 64 + j * 16 + llo;                                \
                bf[j] = *(const bf16x8*)&bL[BUF][r * 64 + ((q ^ (r & 7)) << 3)];\
            }                                                                  \
            _Pragma("unroll")                                                  \
            for (int i = 0; i < 4; ++i)                                        \
                _Pragma("unroll")                                              \
                for (int j = 0; j < 4; ++j)                                    \
                    acc[i][j] = __builtin_amdgcn_mfma_f32_16x16x32_bf16(       \
                        af[i], bf[j], acc[i][j], 0, 0, 0);                     \
        }                                                                      \
    }

    stage2(xa, ba, aL[0], bL[0], tid, 1024);
    __syncthreads();
    int cur = 0;
    for (int kt = 0; kt < 15; ++kt) {
        stage2(xa + (kt + 1) * 64, ba + (kt + 1) * 64, aL[cur ^ 1], bL[cur ^ 1], tid, 1024);
        GG_COMPUTE(cur);
        __syncthreads();   // drains prefetch vmcnt + orders dbuf reuse
        cur ^= 1;
    }
    GG_COMPUTE(cur);       // kt=15; reads buf 1, epilogue reuses buf 0 (safe)

    // ---- epilogue: pair even/odd lanes (gate/up), SiLU, repack via LDS ----
    unsigned short (*xt)[64] = (unsigned short(*)[64]) & aL[0][0];  // 128x64
#pragma unroll
    for (int i = 0; i < 4; ++i)
#pragma unroll
        for (int r = 0; r < 4; ++r) {
            int rloc = wr * 64 + i * 16 + (lhi << 2) + r;
#pragma unroll
            for (int j = 0; j < 4; ++j) {
                float v = acc[i][j][r];
                float p = __shfl_xor(v, 1, 64);
                float g = (llo & 1) ? p : v;
                float u = (llo & 1) ? v : p;
                float s = (g / (1.0f + __expf(-g))) * u;
                xt[rloc][wc * 32 + j * 8 + (llo >> 1)] = f2bf(s);
            }
        }
    __syncthreads();
    // coalesced 16B stores: 1024 chunks, 4 per thread
    unsigned short* xg = x3 + (long)mt * 128 * 512 + nt * 64;
#pragma unroll
    for (int i = 0; i < 4; ++i) {
        int c = i * 256 + tid;
        int row = c >> 3, cc = c & 7;
        *(bf16x8*)(xg + (long)row * 512 + cc * 8) = *(const bf16x8*)&xt[row][cc * 8];
    }
#undef GG_COMPUTE
}

// ---------------------------------------------------------------------------
// Kernel 2: out = x3 @ w3t (M x 1024 fp32). Same dbuf 2-phase structure.
// BM=128, BN=128, BK=64, K=512 -> 8 steps.
// ---------------------------------------------------------------------------
__global__ __launch_bounds__(256, 2)
void down_gemm(const unsigned short* __restrict__ x3,
               const unsigned short* __restrict__ w3t,
               float* __restrict__ out) {
    __shared__ unsigned short aL[2][8192];
    __shared__ unsigned short bL[2][8192];

    const int tid = threadIdx.x;
    const int lane = tid & 63;
    const int wv = tid >> 6;
    const int wr = wv >> 1, wc = wv & 1;
    const int lhi = lane >> 4, llo = lane & 15;

    int bid = blockIdx.x;                      // 8192 blocks
    int wgid = (bid & 7) * 1024 + (bid >> 3);
    const int mt = wgid >> 3, nt = wgid & 7;
    const unsigned short* xa = x3 + (long)mt * 128 * 512;
    const unsigned short* ba = w3t + (long)nt * 128 * 512;

    f32x4 acc[4][4];
#pragma unroll
    for (int i = 0; i < 4; ++i)
#pragma unroll
        for (int j = 0; j < 4; ++j) acc[i][j] = (f32x4){0.f, 0.f, 0.f, 0.f};

#define DG_COMPUTE(BUF)                                                        \
    {                                                                          \
        _Pragma("unroll")                                                      \
        for (int kq = 0; kq < 2; ++kq) {                                       \
            const int q = kq * 4 + lhi;                                        \
            bf16x8 af[4], bf[4];                                               \
            _Pragma("unroll")                                                  \
            for (int i = 0; i < 4; ++i) {                                      \
                int r = wr * 64 + i * 16 + llo;                                \
                af[i] = *(const bf16x8*)&aL[BUF][r * 64 + ((q ^ (r & 7)) << 3)];\
            }                                                                  \
            _Pragma("unroll")                                                  \
            for (int j = 0; j < 4; ++j) {                                      \
                int r = wc * 64 + j * 16 + llo;                                \
                bf[j] = *(const bf16x8*)&bL[BUF][r * 64 + ((q ^ (r & 7)) << 3)];\
            }                                                                  \
            _Pragma("unroll")                                                  \
            for (int i = 0; i < 4; ++i)                                        \
                _Pragma("unroll")                                              \
                for (int j = 0; j < 4; ++j)                                    \
                    acc[i][j] = __builtin_amdgcn_mfma_f32_16x16x32_bf16(       \
                        af[i], bf[j], acc[i][j], 0, 0, 0);                     \
        }                                                                      \
    }

    stage2(xa, ba, aL[0], bL[0], tid, 512);
    __syncthreads();
    int cur = 0;
    for (int kt = 0; kt < 7; ++kt) {
        stage2(xa + (kt + 1) * 64, ba + (kt + 1) * 64, aL[cur ^ 1], bL[cur ^ 1], tid, 512);
        DG_COMPUTE(cur);
        __syncthreads();
        cur ^= 1;
    }
    DG_COMPUTE(cur);

    float* op = out + (long)mt * 128 * 1024 + nt * 128;
#pragma unroll
    for (int i = 0; i < 4; ++i)
#pragma unroll
        for (int r = 0; r < 4; ++r) {
            int rloc = wr * 64 + i * 16 + (lhi << 2) + r;
#pragma unroll
            for (int j = 0; j < 4; ++j)
                op[(long)rloc * 1024 + wc * 64 + j * 16 + llo] = acc[i][j][r];
        }
#undef DG_COMPUTE
}

// ---------------------------------------------------------------------------
extern "C" void kernel_launch(void* const* d_in, const int* in_sizes, int n_in,
                              void* d_out, int out_size, void* d_ws, size_t ws_size,
                              hipStream_t stream) {
    const float* x  = (const float*)d_in[0];
    const float* w0 = (const float*)d_in[1];
    const float* w1 = (const float*)d_in[2];
    const float* w2 = (const float*)d_in[3];
    const float* w3 = (const float*)d_in[4];
    float* out = (float*)d_out;

    unsigned short* w12t = (unsigned short*)d_ws;           // 1024*1024 bf16 = 2MB
    unsigned short* w3t  = w12t + 1024 * 1024;              // 1MB
    unsigned short* x3   = w3t + 1024 * 512;                // 128MB
    unsigned short* xb   = x3 + (size_t)131072 * 512;       // 256MB

    prep_w<<<dim3(6144), dim3(256), 0, stream>>>(w0, w1, w2, w3, w12t, w3t);
    prep_x<<<dim3(2048), dim3(256), 0, stream>>>(x, xb);
    gate_gemm<<<dim3(8192), dim3(256), 0, stream>>>(xb, w12t, x3);
    down_gemm<<<dim3(8192), dim3(256), 0, stream>>>(x3, w3t, out);
}

// Round 4
// 719.718 us; speedup vs baseline: 1.4488x; 1.2749x over previous
//
#include <hip/hip_runtime.h>
#include <cstdint>

typedef __attribute__((ext_vector_type(4))) float f32x4;
typedef __attribute__((ext_vector_type(8))) short bf16x8;
typedef __attribute__((ext_vector_type(4))) short bf16x4;

#define DEV static __device__ __forceinline__

// round-to-nearest-even f32 -> bf16 (bit pattern)
DEV unsigned short f2bf(float f) {
    union { float f; unsigned int u; } v; v.f = f;
    unsigned int u = v.u;
    return (unsigned short)((u + 0x7FFFu + ((u >> 16) & 1u)) >> 16);
}

// async global->LDS 16B per lane; LDS dest = wave-uniform base + lane*16
DEV void async_cp16(const void* g, void* l) {
    __builtin_amdgcn_global_load_lds(
        (const __attribute__((address_space(1))) unsigned int*)g,
        (__attribute__((address_space(3))) unsigned int*)l,
        16, 0, 0);
}

// stage one 128x64 bf16 half-tile (16KB): 512 threads x 2 chunks of 16B.
// linear LDS dest, inverse-swizzled global source (involution: slot^=(row&7)).
DEV void stage_half(const unsigned short* __restrict__ g, long kofs,
                    unsigned short* l, int tid, int gpitch) {
#pragma unroll
    for (int i = 0; i < 2; ++i) {
        int c = i * 512 + tid;
        int row = c >> 3;
        int ss = (c & 7) ^ (row & 7);
        async_cp16(g + (long)row * gpitch + kofs + ss * 8,
                   l + (i * 512 + (tid & 448)) * 8);
    }
}

// ---------------------------------------------------------------------------
// 256x256 8-wave GEMM core. BK=64, NT K-tiles, dbuf'd 128KB LDS.
// lds layout (ushort idx): A(d,h) = (d*2+h)*8192 ; B(d,h) = 32768+(d*2+h)*8192
// Wave (wr=wv>>2, wcq=wv&3) owns C rows [wr*128,+128) x cols [wcq*64,+64).
// Per K-tile: 4 phases (qm,qn) = (0,0),(0,1),(1,0),(1,1); A cached per qm,
// both B quadrant sets cached -> 24 ds_read_b128 per K-tile (minimum).
// Prefetch next K-tile at phases 0-1; single vmcnt(0) at end of phase 3.
// ---------------------------------------------------------------------------
template <int NT>
DEV void gemm256(const unsigned short* __restrict__ gA,
                 const unsigned short* __restrict__ gB,
                 const int gpitch, unsigned short* lds,
                 f32x4 (&acc)[8][4], const int tid) {
    const int lane = tid & 63;
    const int wv = tid >> 6;
    const int wr = wv >> 2;
    const int wcq = wv & 3;
    const int lhi = lane >> 4, llo = lane & 15;
    const int hb = wcq >> 1;           // B half-tile index
    const int br0 = (wcq & 1) * 64;    // B row base within half

#define MFMA8(AF, BF, RI0, CJ0)                                               \
    _Pragma("unroll") for (int kq = 0; kq < 2; ++kq)                          \
    _Pragma("unroll") for (int i = 0; i < 4; ++i)                             \
    _Pragma("unroll") for (int j = 0; j < 2; ++j)                             \
        acc[RI0 + i][CJ0 + j] = __builtin_amdgcn_mfma_f32_16x16x32_bf16(      \
            AF[kq][i], BF[kq][j], acc[RI0 + i][CJ0 + j], 0, 0, 0);

    // prologue: K-tile 0 -> buffer 0
#pragma unroll
    for (int h = 0; h < 2; ++h) {
        stage_half(gA + (long)h * 128 * gpitch, 0, lds + h * 8192, tid, gpitch);
        stage_half(gB + (long)h * 128 * gpitch, 0, lds + 32768 + h * 8192, tid, gpitch);
    }
    asm volatile("s_waitcnt vmcnt(0)" ::: "memory");
    __builtin_amdgcn_s_barrier();

    bf16x8 af[2][4], bf0[2][2], bf1[2][2];

    for (int kt = 0; kt < NT; ++kt) {
        const int cur = kt & 1, nxt = cur ^ 1;
        const unsigned short* lA = lds + (cur * 2 + wr) * 8192;
        const unsigned short* lB = lds + 32768 + (cur * 2 + hb) * 8192;
        const bool pf = (kt + 1 < NT);
        const long kofs = (long)(kt + 1) * 64;

        // ---- phase 0: read A(qm=0) + B(qn=0); prefetch next A halves ----
#pragma unroll
        for (int kq = 0; kq < 2; ++kq) {
            const int q = kq * 4 + lhi;
#pragma unroll
            for (int i = 0; i < 4; ++i) {
                int r = i * 16 + llo;
                af[kq][i] = *(const bf16x8*)&lA[r * 64 + ((q ^ (r & 7)) << 3)];
            }
#pragma unroll
            for (int j = 0; j < 2; ++j) {
                int r = br0 + j * 16 + llo;
                bf0[kq][j] = *(const bf16x8*)&lB[r * 64 + ((q ^ (r & 7)) << 3)];
            }
        }
        if (pf) {
            stage_half(gA, kofs, lds + (nxt * 2 + 0) * 8192, tid, gpitch);
            stage_half(gA + (long)128 * gpitch, kofs, lds + (nxt * 2 + 1) * 8192, tid, gpitch);
        }
        __builtin_amdgcn_s_barrier();
        asm volatile("s_waitcnt lgkmcnt(0)");
        __builtin_amdgcn_sched_barrier(0);
        __builtin_amdgcn_s_setprio(1);
        MFMA8(af, bf0, 0, 0)
        __builtin_amdgcn_s_setprio(0);
        __builtin_amdgcn_s_barrier();

        // ---- phase 1: read B(qn=1); prefetch next B halves --------------
#pragma unroll
        for (int kq = 0; kq < 2; ++kq) {
            const int q = kq * 4 + lhi;
#pragma unroll
            for (int j = 0; j < 2; ++j) {
                int r = br0 + 32 + j * 16 + llo;
                bf1[kq][j] = *(const bf16x8*)&lB[r * 64 + ((q ^ (r & 7)) << 3)];
            }
        }
        if (pf) {
            stage_half(gB, kofs, lds + 32768 + (nxt * 2 + 0) * 8192, tid, gpitch);
            stage_half(gB + (long)128 * gpitch, kofs, lds + 32768 + (nxt * 2 + 1) * 8192, tid, gpitch);
        }
        __builtin_amdgcn_s_barrier();
        asm volatile("s_waitcnt lgkmcnt(0)");
        __builtin_amdgcn_sched_barrier(0);
        __builtin_amdgcn_s_setprio(1);
        MFMA8(af, bf1, 0, 2)
        __builtin_amdgcn_s_setprio(0);
        __builtin_amdgcn_s_barrier();

        // ---- phase 2: read A(qm=1) ---------------------------------------
#pragma unroll
        for (int kq = 0; kq < 2; ++kq) {
            const int q = kq * 4 + lhi;
#pragma unroll
            for (int i = 0; i < 4; ++i) {
                int r = 64 + i * 16 + llo;
                af[kq][i] = *(const bf16x8*)&lA[r * 64 + ((q ^ (r & 7)) << 3)];
            }
        }
        __builtin_amdgcn_s_barrier();
        asm volatile("s_waitcnt lgkmcnt(0)");
        __builtin_amdgcn_sched_barrier(0);
        __builtin_amdgcn_s_setprio(1);
        MFMA8(af, bf0, 4, 0)
        __builtin_amdgcn_s_setprio(0);
        __builtin_amdgcn_s_barrier();

        // ---- phase 3: no reads; MFMA overlaps prefetch drain -------------
        __builtin_amdgcn_s_setprio(1);
        MFMA8(af, bf1, 4, 2)
        __builtin_amdgcn_s_setprio(0);
        if (pf) asm volatile("s_waitcnt vmcnt(0)" ::: "memory");
        __builtin_amdgcn_s_barrier();
        __builtin_amdgcn_sched_barrier(0);
    }
#undef MFMA8
}

// ---------------------------------------------------------------------------
// Kernel 0: weight prep.
//  w12t[n][k]: n even -> bf16(w0[k]*w1[k][n/2]), n odd -> bf16(w0[k]*w2[k][n/2])
//  w3t[j][n] = bf16(w3[n][j])   (1024 x 512, n contiguous)
// ---------------------------------------------------------------------------
__global__ void prep_w(const float* __restrict__ w0, const float* __restrict__ w1,
                       const float* __restrict__ w2, const float* __restrict__ w3,
                       unsigned short* __restrict__ w12t, unsigned short* __restrict__ w3t) {
    int t = blockIdx.x * 256 + threadIdx.x;
    if (t < 1048576) {
        int n = t >> 10, k = t & 1023;
        const float* src = (n & 1) ? w2 : w1;
        w12t[t] = f2bf(w0[k] * src[k * 512 + (n >> 1)]);
    } else {
        int idx = t - 1048576;
        int j = idx >> 9, n = idx & 511;
        w3t[idx] = f2bf(w3[n * 1024 + j]);
    }
}

// ---------------------------------------------------------------------------
// Kernel 0b: RMSNorm fold. xb[row][k] = bf16(x[row][k] * rsqrt(mean(x^2)))
// ---------------------------------------------------------------------------
__global__ __launch_bounds__(256)
void prep_x(const float* __restrict__ x, unsigned short* __restrict__ xb) {
    const int wv = threadIdx.x >> 6, lane = threadIdx.x & 63;
    const int stride = gridDim.x * 4;
    for (int row = blockIdx.x * 4 + wv; row < 131072; row += stride) {
        const float* xr = x + (long)row * 1024;
        f32x4 v[4];
        float s = 0.f;
#pragma unroll
        for (int c = 0; c < 4; ++c) {
            v[c] = *(const f32x4*)(xr + c * 256 + lane * 4);
            s += v[c].x * v[c].x + v[c].y * v[c].y + v[c].z * v[c].z + v[c].w * v[c].w;
        }
#pragma unroll
        for (int off = 32; off > 0; off >>= 1) s += __shfl_xor(s, off, 64);
        float l = rsqrtf(s * (1.0f / 1024.0f));
        unsigned short* xo = xb + (long)row * 1024;
#pragma unroll
        for (int c = 0; c < 4; ++c) {
            bf16x4 b;
            b.x = (short)f2bf(v[c].x * l);
            b.y = (short)f2bf(v[c].y * l);
            b.z = (short)f2bf(v[c].z * l);
            b.w = (short)f2bf(v[c].w * l);
            *(bf16x4*)(xo + c * 256 + lane * 4) = b;
        }
    }
}

// ---------------------------------------------------------------------------
// Kernel 1: x3 = silu_gate(xb @ w12t^T). 256x256 tile, K=1024 -> 16 K-tiles.
// ---------------------------------------------------------------------------
__global__ __launch_bounds__(512, 2)
void gate_gemm(const unsigned short* __restrict__ xb,
               const unsigned short* __restrict__ w12t,
               unsigned short* __restrict__ x3) {
    __shared__ unsigned short lds[65536];    // 128 KB
    const int tid = threadIdx.x;
    const int lane = tid & 63;
    const int wv = tid >> 6;
    const int wr = wv >> 2, wcq = wv & 3;
    const int lhi = lane >> 4, llo = lane & 15;

    int bid = blockIdx.x;                    // 2048 blocks
    int wgid = (bid & 7) * 256 + (bid >> 3); // bijective XCD chunks
    const int mt = wgid >> 2, nt = wgid & 3;

    f32x4 acc[8][4];
#pragma unroll
    for (int i = 0; i < 8; ++i)
#pragma unroll
        for (int j = 0; j < 4; ++j) acc[i][j] = (f32x4){0.f, 0.f, 0.f, 0.f};

    gemm256<16>(xb + (long)mt * 256 * 1024, w12t + (long)nt * 256 * 1024,
                1024, lds, acc, tid);

    // ---- epilogue: pair even/odd interleaved cols (gate/up), SiLU, repack --
    // repack tile [256][136] ushorts (padded: +8 breaks 4-row bank cycle)
#pragma unroll
    for (int ri = 0; ri < 8; ++ri)
#pragma unroll
        for (int rr = 0; rr < 4; ++rr) {
            int R = wr * 128 + ri * 16 + lhi * 4 + rr;
#pragma unroll
            for (int cj = 0; cj < 4; ++cj) {
                float v = acc[ri][cj][rr];
                float p = __shfl_xor(v, 1, 64);
                float g = (lane & 1) ? p : v;
                float u = (lane & 1) ? v : p;
                float s = (g / (1.0f + __expf(-g))) * u;
                if (!(lane & 1))
                    lds[R * 136 + wcq * 32 + cj * 8 + (llo >> 1)] = f2bf(s);
            }
        }
    __syncthreads();
    unsigned short* xg = x3 + (long)(mt * 256) * 512 + nt * 128;
#pragma unroll
    for (int i = 0; i < 8; ++i) {
        int c = i * 512 + tid;               // 4096 chunks of 16B
        int row = c >> 4, ch = c & 15;
        *(bf16x8*)(xg + (long)row * 512 + ch * 8) = *(const bf16x8*)&lds[row * 136 + ch * 8];
    }
}

// ---------------------------------------------------------------------------
// Kernel 2: out = x3 @ w3t (M x 1024 fp32). 256x256 tile, K=512 -> 8 K-tiles.
// ---------------------------------------------------------------------------
__global__ __launch_bounds__(512, 2)
void down_gemm(const unsigned short* __restrict__ x3,
               const unsigned short* __restrict__ w3t,
               float* __restrict__ out) {
    __shared__ unsigned short lds[65536];
    const int tid = threadIdx.x;
    const int lane = tid & 63;
    const int wv = tid >> 6;
    const int wr = wv >> 2, wcq = wv & 3;
    const int lhi = lane >> 4, llo = lane & 15;

    int bid = blockIdx.x;                    // 2048 blocks
    int wgid = (bid & 7) * 256 + (bid >> 3);
    const int mt = wgid >> 2, nt = wgid & 3;

    f32x4 acc[8][4];
#pragma unroll
    for (int i = 0; i < 8; ++i)
#pragma unroll
        for (int j = 0; j < 4; ++j) acc[i][j] = (f32x4){0.f, 0.f, 0.f, 0.f};

    gemm256<8>(x3 + (long)mt * 256 * 512, w3t + (long)nt * 256 * 512,
               512, lds, acc, tid);

    float* op = out + (long)(mt * 256) * 1024 + nt * 256;
#pragma unroll
    for (int ri = 0; ri < 8; ++ri)
#pragma unroll
        for (int rr = 0; rr < 4; ++rr) {
            int R = wr * 128 + ri * 16 + lhi * 4 + rr;
#pragma unroll
            for (int cj = 0; cj < 4; ++cj)
                op[(long)R * 1024 + wcq * 64 + cj * 16 + llo] = acc[ri][cj][rr];
        }
}

// ---------------------------------------------------------------------------
extern "C" void kernel_launch(void* const* d_in, const int* in_sizes, int n_in,
                              void* d_out, int out_size, void* d_ws, size_t ws_size,
                              hipStream_t stream) {
    const float* x  = (const float*)d_in[0];
    const float* w0 = (const float*)d_in[1];
    const float* w1 = (const float*)d_in[2];
    const float* w2 = (const float*)d_in[3];
    const float* w3 = (const float*)d_in[4];
    float* out = (float*)d_out;

    unsigned short* w12t = (unsigned short*)d_ws;           // 2MB
    unsigned short* w3t  = w12t + 1024 * 1024;              // 1MB
    unsigned short* x3   = w3t + 1024 * 512;                // 128MB
    unsigned short* xb   = x3 + (size_t)131072 * 512;       // 256MB

    prep_w<<<dim3(6144), dim3(256), 0, stream>>>(w0, w1, w2, w3, w12t, w3t);
    prep_x<<<dim3(2048), dim3(256), 0, stream>>>(x, xb);
    gate_gemm<<<dim3(2048), dim3(512), 0, stream>>>(xb, w12t, x3);
    down_gemm<<<dim3(2048), dim3(512), 0, stream>>>(x3, w3t, out);
}

// Round 5
// 703.011 us; speedup vs baseline: 1.4833x; 1.0238x over previous
//
#include <hip/hip_runtime.h>
#include <cstdint>

typedef __attribute__((ext_vector_type(4))) float f32x4;
typedef __attribute__((ext_vector_type(8))) short bf16x8;
typedef __attribute__((ext_vector_type(4))) short bf16x4;

#define DEV static __device__ __forceinline__

// round-to-nearest-even f32 -> bf16 (bit pattern)
DEV unsigned short f2bf(float f) {
    union { float f; unsigned int u; } v; v.f = f;
    unsigned int u = v.u;
    return (unsigned short)((u + 0x7FFFu + ((u >> 16) & 1u)) >> 16);
}

// async global->LDS 16B per lane; LDS dest = wave-uniform base + lane*16
DEV void async_cp16(const void* g, void* l) {
    __builtin_amdgcn_global_load_lds(
        (const __attribute__((address_space(1))) unsigned int*)g,
        (__attribute__((address_space(3))) unsigned int*)l,
        16, 0, 0);
}

// stage one 128x64 bf16 half-tile (16KB): 512 threads x 2 chunks of 16B.
// linear LDS dest, inverse-swizzled global source (involution: slot^=(row&7)).
DEV void stage_half(const unsigned short* __restrict__ g, long kofs,
                    unsigned short* l, int tid, int gpitch) {
#pragma unroll
    for (int i = 0; i < 2; ++i) {
        int c = i * 512 + tid;
        int row = c >> 3;
        int ss = (c & 7) ^ (row & 7);
        async_cp16(g + (long)row * gpitch + kofs + ss * 8,
                   l + (i * 512 + (tid & 448)) * 8);
    }
}

// ---------------------------------------------------------------------------
// 256x256 8-wave GEMM core. BK=64, NT K-tiles, dbuf'd 128KB LDS.
// lds layout (ushort idx): A(d,h) = (d*2+h)*8192 ; B(d,h) = 32768+(d*2+h)*8192
// Wave (wr=wv>>2, wcq=wv&3) owns C rows [wr*128,+128) x cols [wcq*64,+64).
// 4 phases per K-tile, 1 half-tile staged per phase (issue order per tile t:
// A[nxt,h1]@ph0, B[nxt,h0]@ph1, B[nxt,h1]@ph2, A[buf(t+2),h0]@ph3), so the
// pre-consumption wait is a COUNTED s_waitcnt vmcnt(2) (T4), never 0 except
// at the tail. Safety: buffer cur's last ds_read is in ph2 (barrier'd), so
// ph3 may stage tile t+2's A-half into cur; buffer nxt's last read (tile t-1)
// ended at its ph2 barrier, so ph0..ph2 staging into nxt is safe.
// ---------------------------------------------------------------------------
template <int NT>
DEV void gemm256(const unsigned short* __restrict__ gA,
                 const unsigned short* __restrict__ gB,
                 const int gpitch, unsigned short* lds,
                 f32x4 (&acc)[8][4], const int tid) {
    const int lane = tid & 63;
    const int wv = tid >> 6;
    const int wr = wv >> 2;
    const int wcq = wv & 3;
    const int lhi = lane >> 4, llo = lane & 15;
    const int hb = wcq >> 1;           // B half-tile index
    const int br0 = (wcq & 1) * 64;    // B row base within half

#define MFMA8(AF, BF, RI0, CJ0)                                               \
    _Pragma("unroll") for (int kq = 0; kq < 2; ++kq)                          \
    _Pragma("unroll") for (int i = 0; i < 4; ++i)                             \
    _Pragma("unroll") for (int j = 0; j < 2; ++j)                             \
        acc[RI0 + i][CJ0 + j] = __builtin_amdgcn_mfma_f32_16x16x32_bf16(      \
            AF[kq][i], BF[kq][j], acc[RI0 + i][CJ0 + j], 0, 0, 0);

    // prologue: K-tile 0 (8 loads) + tile 1's A[h0] (2 loads), wait buf0 only
    stage_half(gA, 0, lds + 0 * 8192, tid, gpitch);                    // A[0,h0]
    stage_half(gA + (long)128 * gpitch, 0, lds + 1 * 8192, tid, gpitch); // A[0,h1]
    stage_half(gB, 0, lds + 32768 + 0 * 8192, tid, gpitch);            // B[0,h0]
    stage_half(gB + (long)128 * gpitch, 0, lds + 32768 + 1 * 8192, tid, gpitch); // B[0,h1]
    if (NT > 1) {
        stage_half(gA, 64, lds + 2 * 8192, tid, gpitch);               // A[1,h0]
        asm volatile("s_waitcnt vmcnt(2)" ::: "memory");
    } else {
        asm volatile("s_waitcnt vmcnt(0)" ::: "memory");
    }
    __builtin_amdgcn_s_barrier();

    bf16x8 af[2][4], bf0[2][2], bf1[2][2];

    for (int kt = 0; kt < NT; ++kt) {
        const int cur = kt & 1, nxt = cur ^ 1;
        const unsigned short* lA = lds + (cur * 2 + wr) * 8192;
        const unsigned short* lB = lds + 32768 + (cur * 2 + hb) * 8192;
        const bool pf1 = (kt + 1 < NT);
        const bool pf2 = (kt + 2 < NT);
        const long k1 = (long)(kt + 1) * 64;
        const long k2 = (long)(kt + 2) * 64;

        // ---- phase 0: read A(rows 0-63) + B(rows br0..+31); stage A[nxt,h1]
#pragma unroll
        for (int kq = 0; kq < 2; ++kq) {
            const int q = kq * 4 + lhi;
#pragma unroll
            for (int i = 0; i < 4; ++i) {
                int r = i * 16 + llo;
                af[kq][i] = *(const bf16x8*)&lA[r * 64 + ((q ^ (r & 7)) << 3)];
            }
#pragma unroll
            for (int j = 0; j < 2; ++j) {
                int r = br0 + j * 16 + llo;
                bf0[kq][j] = *(const bf16x8*)&lB[r * 64 + ((q ^ (r & 7)) << 3)];
            }
        }
        if (pf1)
            stage_half(gA + (long)128 * gpitch, k1, lds + (nxt * 2 + 1) * 8192, tid, gpitch);
        __builtin_amdgcn_s_barrier();
        asm volatile("s_waitcnt lgkmcnt(0)");
        __builtin_amdgcn_sched_barrier(0);
        __builtin_amdgcn_s_setprio(1);
        MFMA8(af, bf0, 0, 0)
        __builtin_amdgcn_s_setprio(0);
        __builtin_amdgcn_s_barrier();

        // ---- phase 1: read B(rows br0+32..63); stage B[nxt,h0] ----------
#pragma unroll
        for (int kq = 0; kq < 2; ++kq) {
            const int q = kq * 4 + lhi;
#pragma unroll
            for (int j = 0; j < 2; ++j) {
                int r = br0 + 32 + j * 16 + llo;
                bf1[kq][j] = *(const bf16x8*)&lB[r * 64 + ((q ^ (r & 7)) << 3)];
            }
        }
        if (pf1)
            stage_half(gB, k1, lds + 32768 + (nxt * 2 + 0) * 8192, tid, gpitch);
        __builtin_amdgcn_s_barrier();
        asm volatile("s_waitcnt lgkmcnt(0)");
        __builtin_amdgcn_sched_barrier(0);
        __builtin_amdgcn_s_setprio(1);
        MFMA8(af, bf1, 0, 2)
        __builtin_amdgcn_s_setprio(0);
        __builtin_amdgcn_s_barrier();

        // ---- phase 2: read A(rows 64-127); stage B[nxt,h1] --------------
#pragma unroll
        for (int kq = 0; kq < 2; ++kq) {
            const int q = kq * 4 + lhi;
#pragma unroll
            for (int i = 0; i < 4; ++i) {
                int r = 64 + i * 16 + llo;
                af[kq][i] = *(const bf16x8*)&lA[r * 64 + ((q ^ (r & 7)) << 3)];
            }
        }
        if (pf1)
            stage_half(gB + (long)128 * gpitch, k1, lds + 32768 + (nxt * 2 + 1) * 8192, tid, gpitch);
        __builtin_amdgcn_s_barrier();
        asm volatile("s_waitcnt lgkmcnt(0)");
        __builtin_amdgcn_sched_barrier(0);
        __builtin_amdgcn_s_setprio(1);
        MFMA8(af, bf0, 4, 0)
        __builtin_amdgcn_s_setprio(0);
        __builtin_amdgcn_s_barrier();

        // ---- phase 3: stage A[buf(kt+2),h0] early; MFMA; counted vmcnt --
        if (pf2)
            stage_half(gA, k2, lds + (cur * 2 + 0) * 8192, tid, gpitch);
        __builtin_amdgcn_s_setprio(1);
        MFMA8(af, bf1, 4, 2)
        __builtin_amdgcn_s_setprio(0);
        if (pf1) {
            if (pf2) asm volatile("s_waitcnt vmcnt(2)" ::: "memory");
            else     asm volatile("s_waitcnt vmcnt(0)" ::: "memory");
        }
        __builtin_amdgcn_s_barrier();
        __builtin_amdgcn_sched_barrier(0);
    }
#undef MFMA8
}

// ---------------------------------------------------------------------------
// Kernel 0: weight prep.
//  w12t[n][k]: n even -> bf16(w0[k]*w1[k][n/2]), n odd -> bf16(w0[k]*w2[k][n/2])
//  w3t[j][n] = bf16(w3[n][j])   (1024 x 512, n contiguous)
// ---------------------------------------------------------------------------
__global__ void prep_w(const float* __restrict__ w0, const float* __restrict__ w1,
                       const float* __restrict__ w2, const float* __restrict__ w3,
                       unsigned short* __restrict__ w12t, unsigned short* __restrict__ w3t) {
    int t = blockIdx.x * 256 + threadIdx.x;
    if (t < 1048576) {
        int n = t >> 10, k = t & 1023;
        const float* src = (n & 1) ? w2 : w1;
        w12t[t] = f2bf(w0[k] * src[k * 512 + (n >> 1)]);
    } else {
        int idx = t - 1048576;
        int j = idx >> 9, n = idx & 511;
        w3t[idx] = f2bf(w3[n * 1024 + j]);
    }
}

// ---------------------------------------------------------------------------
// Kernel 0b: RMSNorm fold. xb[row][k] = bf16(x[row][k] * rsqrt(mean(x^2)))
// ---------------------------------------------------------------------------
__global__ __launch_bounds__(256)
void prep_x(const float* __restrict__ x, unsigned short* __restrict__ xb) {
    const int wv = threadIdx.x >> 6, lane = threadIdx.x & 63;
    const int stride = gridDim.x * 4;
    for (int row = blockIdx.x * 4 + wv; row < 131072; row += stride) {
        const float* xr = x + (long)row * 1024;
        f32x4 v[4];
        float s = 0.f;
#pragma unroll
        for (int c = 0; c < 4; ++c) {
            v[c] = *(const f32x4*)(xr + c * 256 + lane * 4);
            s += v[c].x * v[c].x + v[c].y * v[c].y + v[c].z * v[c].z + v[c].w * v[c].w;
        }
#pragma unroll
        for (int off = 32; off > 0; off >>= 1) s += __shfl_xor(s, off, 64);
        float l = rsqrtf(s * (1.0f / 1024.0f));
        unsigned short* xo = xb + (long)row * 1024;
#pragma unroll
        for (int c = 0; c < 4; ++c) {
            bf16x4 b;
            b.x = (short)f2bf(v[c].x * l);
            b.y = (short)f2bf(v[c].y * l);
            b.z = (short)f2bf(v[c].z * l);
            b.w = (short)f2bf(v[c].w * l);
            *(bf16x4*)(xo + c * 256 + lane * 4) = b;
        }
    }
}

// ---------------------------------------------------------------------------
// Kernel 1: x3 = silu_gate(xb @ w12t^T). 256x256 tile, K=1024 -> 16 K-tiles.
// ---------------------------------------------------------------------------
__global__ __launch_bounds__(512, 2)
void gate_gemm(const unsigned short* __restrict__ xb,
               const unsigned short* __restrict__ w12t,
               unsigned short* __restrict__ x3) {
    __shared__ unsigned short lds[65536];    // 128 KB
    const int tid = threadIdx.x;
    const int lane = tid & 63;
    const int wv = tid >> 6;
    const int wr = wv >> 2, wcq = wv & 3;
    const int lhi = lane >> 4, llo = lane & 15;

    int bid = blockIdx.x;                    // 2048 blocks
    int wgid = (bid & 7) * 256 + (bid >> 3); // bijective XCD chunks
    const int mt = wgid >> 2, nt = wgid & 3;

    f32x4 acc[8][4];
#pragma unroll
    for (int i = 0; i < 8; ++i)
#pragma unroll
        for (int j = 0; j < 4; ++j) acc[i][j] = (f32x4){0.f, 0.f, 0.f, 0.f};

    gemm256<16>(xb + (long)mt * 256 * 1024, w12t + (long)nt * 256 * 1024,
                1024, lds, acc, tid);

    // ---- epilogue: pair even/odd interleaved cols (gate/up), SiLU, repack --
    // repack tile [256][144] ushorts (288B pitch: lhi groups on distinct banks)
#pragma unroll
    for (int ri = 0; ri < 8; ++ri)
#pragma unroll
        for (int rr = 0; rr < 4; ++rr) {
            int R = wr * 128 + ri * 16 + lhi * 4 + rr;
#pragma unroll
            for (int cj = 0; cj < 4; ++cj) {
                float v = acc[ri][cj][rr];
                float p = __shfl_xor(v, 1, 64);
                float g = (lane & 1) ? p : v;
                float u = (lane & 1) ? v : p;
                float s = (g / (1.0f + __expf(-g))) * u;
                if (!(lane & 1))
                    lds[R * 144 + wcq * 32 + cj * 8 + (llo >> 1)] = f2bf(s);
            }
        }
    __syncthreads();
    unsigned short* xg = x3 + (long)(mt * 256) * 512 + nt * 128;
#pragma unroll
    for (int i = 0; i < 8; ++i) {
        int c = i * 512 + tid;               // 4096 chunks of 16B
        int row = c >> 4, ch = c & 15;
        *(bf16x8*)(xg + (long)row * 512 + ch * 8) = *(const bf16x8*)&lds[row * 144 + ch * 8];
    }
}

// ---------------------------------------------------------------------------
// Kernel 2: out = x3 @ w3t (M x 1024 fp32). 256x256 tile, K=512 -> 8 K-tiles.
// ---------------------------------------------------------------------------
__global__ __launch_bounds__(512, 2)
void down_gemm(const unsigned short* __restrict__ x3,
               const unsigned short* __restrict__ w3t,
               float* __restrict__ out) {
    __shared__ unsigned short lds[65536];
    const int tid = threadIdx.x;
    const int lane = tid & 63;
    const int wv = tid >> 6;
    const int wr = wv >> 2, wcq = wv & 3;
    const int lhi = lane >> 4, llo = lane & 15;

    int bid = blockIdx.x;                    // 2048 blocks
    int wgid = (bid & 7) * 256 + (bid >> 3);
    const int mt = wgid >> 2, nt = wgid & 3;

    f32x4 acc[8][4];
#pragma unroll
    for (int i = 0; i < 8; ++i)
#pragma unroll
        for (int j = 0; j < 4; ++j) acc[i][j] = (f32x4){0.f, 0.f, 0.f, 0.f};

    gemm256<8>(x3 + (long)mt * 256 * 512, w3t + (long)nt * 256 * 512,
               512, lds, acc, tid);

    float* op = out + (long)(mt * 256) * 1024 + nt * 256;
#pragma unroll
    for (int ri = 0; ri < 8; ++ri)
#pragma unroll
        for (int rr = 0; rr < 4; ++rr) {
            int R = wr * 128 + ri * 16 + lhi * 4 + rr;
#pragma unroll
            for (int cj = 0; cj < 4; ++cj)
                op[(long)R * 1024 + wcq * 64 + cj * 16 + llo] = acc[ri][cj][rr];
        }
}

// ---------------------------------------------------------------------------
extern "C" void kernel_launch(void* const* d_in, const int* in_sizes, int n_in,
                              void* d_out, int out_size, void* d_ws, size_t ws_size,
                              hipStream_t stream) {
    const float* x  = (const float*)d_in[0];
    const float* w0 = (const float*)d_in[1];
    const float* w1 = (const float*)d_in[2];
    const float* w2 = (const float*)d_in[3];
    const float* w3 = (const float*)d_in[4];
    float* out = (float*)d_out;

    unsigned short* w12t = (unsigned short*)d_ws;           // 2MB
    unsigned short* w3t  = w12t + 1024 * 1024;              // 1MB
    unsigned short* x3   = w3t + 1024 * 512;                // 128MB
    unsigned short* xb   = x3 + (size_t)131072 * 512;       // 256MB

    prep_w<<<dim3(6144), dim3(256), 0, stream>>>(w0, w1, w2, w3, w12t, w3t);
    prep_x<<<dim3(2048), dim3(256), 0, stream>>>(x, xb);
    gate_gemm<<<dim3(2048), dim3(512), 0, stream>>>(xb, w12t, x3);
    down_gemm<<<dim3(2048), dim3(512), 0, stream>>>(x3, w3t, out);
}